// Round 5
// baseline (79.166 us; speedup 1.0000x reference)
//
#include <hip/hip_runtime.h>

#define L 4096
#define BLOCK 256
#define LANES 64
#define NWAVE (BLOCK / LANES)     // 4 waves per row
#define NCH (L / LANES)           // 64 chunks of 64
#define CPW (NCH / NWAVE)         // 16 chunks per wave (contiguous segment)
#define VPT (L / 4 / BLOCK)       // float4 loads per thread (= 4)
#define DPAD 64
#define REPS 4
typedef unsigned long long u64;
typedef unsigned u32;
typedef int v2i __attribute__((ext_vector_type(2)));
#define SENT32 0xFFFFFFFFu        // kept marker; real keys <= 0x7F800002

template<int CTRL, int RM>
static __device__ __forceinline__ u32 dpp32(u32 v) {
    u32 s = (u32)__builtin_amdgcn_update_dpp(0, (int)v, CTRL, RM, 0xf, false);
    return v > s ? v : s;   // bound_ctrl=false, old=0 -> identity off-row
}
// Inclusive 64-lane prefix-max (hardware-verified DPP sequence).
static __device__ __forceinline__ u32 scanmax32(u32 v) {
    v = dpp32<0x111, 0xf>(v);  // row_shr:1
    v = dpp32<0x112, 0xf>(v);  // row_shr:2
    v = dpp32<0x114, 0xf>(v);  // row_shr:4
    v = dpp32<0x118, 0xf>(v);  // row_shr:8
    v = dpp32<0x142, 0xa>(v);  // row_bcast:15
    v = dpp32<0x143, 0xc>(v);  // row_bcast:31
    return v;
}

// ---- lane-permutes (R2 hardware-verified equality-select forms) ----
static __device__ __forceinline__ u32 mirror16(u32 v) {
    return (u32)__builtin_amdgcn_update_dpp(0, (int)v, 0x140, 0xf, 0xf, true);
}
static __device__ __forceinline__ u32 xor16sel(u32 v, int lane) {
#if __has_builtin(__builtin_amdgcn_permlane16_swap)
    v2i r = __builtin_amdgcn_permlane16_swap((int)v, (int)v, false, false);
    u32 a = (u32)r.x, b = (u32)r.y;
    return (a == v) ? b : a;           // pick the swapped-in element
#else
    return (u32)__shfl((int)v, lane ^ 16);
#endif
}
static __device__ __forceinline__ u32 xor32sel(u32 v, int lane) {
#if __has_builtin(__builtin_amdgcn_permlane32_swap)
    v2i r = __builtin_amdgcn_permlane32_swap((int)v, (int)v, false, false);
    u32 a = (u32)r.x, b = (u32)r.y;
    return (a == v) ? b : a;           // pick the swapped-in element
#else
    return (u32)__shfl((int)v, lane ^ 32);
#endif
}
// full 64-lane reversal: lane i reads v[63-i]
static __device__ __forceinline__ u32 rev64(u32 v, int lane) {
    return xor32sel(xor16sel(mirror16(v), lane), lane);
}
// half-reversal: lane i reads v[lane^31] == shfl(v, 63-(lane^32))
static __device__ __forceinline__ u32 rev32h(u32 v, int lane) {
    return xor16sel(mirror16(v), lane);
}
static __device__ __forceinline__ u32 readlane32(u32 v, int c) {
#if __has_builtin(__builtin_amdgcn_readlane)
    return (u32)__builtin_amdgcn_readlane((int)v, c);   // c is wave-uniform
#else
    return (u32)__shfl((int)v, c);
#endif
}

// enc[i]: active -> bits(|x|)+1; 0 = none/suppressed; SENT32 = kept.
// R5 structure: 4 waves x 16 chunks. Register-carry soundness: cross-wave
// writes reach only chunk0's lower 32 / chunk(CPW-1)'s upper 32 slots
// (winners live in their own segment, radius 32). Inner chunks 1..CPW-2 have
// NO external channel -> register-carried state is EXACT; boundary chunks are
// re-read fresh from LDS. Out-of-window staleness only over-estimates dead
// neighbors -> defer-only, never a false keep; ties resolved exactly via
// equality ballots (smaller index first = JAX argsort).
// Exact dirty channels (window algebra): chunk KL change at lanes<32 affects
// only KL-1; lanes>=32 only KL+1. supP -> KL-1; supN -> KL+1.
// Insurance: every 32nd pass forces dirty=all (falls back to proven behavior).
template<int KL>
static __device__ __forceinline__ void visit(u32* enc, int seg0, int lane,
                                             u32& alive, u32& dirty,
                                             u32 (&r)[CPW],
                                             u32& ePb, u32& eNb) {
    constexpr u32 SELF = 1u << KL;
    constexpr int KLm1 = (KL > 0) ? KL - 1 : 0;
    constexpr int KLp1 = (KL < CPW - 1) ? KL + 1 : CPW - 1;
    constexpr u32 DLO = (KL == 0) ? 0u : (1u << KLm1);
    constexpr u32 DHI = (KL == CPW - 1) ? 0u : (1u << KLp1);

    if (!__ballot((int)((alive >> KL) & 1u))) return;
    const int q0 = (seg0 + KL) << 6;
    const int p = q0 + lane;
    u32& own = r[KL];
    u32 dumP = 0, dumN = 0;
    u32& prevR = (KL == 0) ? dumP : r[KLm1];
    u32& nextR = (KL == CPW - 1) ? dumN : r[KLp1];

    u32 eC, eP, eN;
    if constexpr (KL == 0) {
        eC = ((volatile u32*)enc)[p];
        eP = ((volatile u32*)enc)[q0 - 64 + lane];
        // relevant external channels: eC any lane; eP upper half only
        bool same = (eC == own) & ((lane < 32) | (eP == ePb));
        if (!(dirty & SELF) && __all((int)same)) return;       // exact skip
        ePb = eP;
        eN = nextR;
    } else if constexpr (KL == CPW - 1) {
        eC = ((volatile u32*)enc)[p];
        eN = ((volatile u32*)enc)[q0 + 64 + lane];
        bool same = (eC == own) & ((lane >= 32) | (eN == eNb));
        if (!(dirty & SELF) && __all((int)same)) return;
        eNb = eN;
        eP = prevR;
    } else {
        if (!(dirty & SELF)) return;   // no external channel exists -> exact skip
        eC = own; eP = prevR; eN = nextR;
    }
    const u32 eC0 = eC;

    bool act = (alive >> KL) & 1u;
    if (act && eC == 0u) { alive &= ~SELF; act = false; }
    if (!__ballot((int)act)) { own = eC; dirty &= ~SELF; return; }

    u32 ePr = rev64(eP, lane);
    u32 S_P = scanmax32(ePr);
    u32 P_n = scanmax32(eN);

    bool conv = false;
    bool anyP = false, anyN = false;
    for (int rep = 0; rep < REPS; ++rep) {
        u32 P_c = scanmax32(eC);
        u32 S_C = scanmax32(rev64(eC, lane));
        // Gil-Werman window-max [p-32,p+32]
        u32 sendS = (lane < 32) ? S_P : S_C;
        u32 sendP = (lane < 32) ? P_n : P_c;
        u32 a1 = rev32h(sendS, lane);      // == shfl(sendS, 63-(lane^32))
        u32 a2 = xor32sel(sendP, lane);    // == shfl(sendP, lane^32)
        u32 wm = a1 > a2 ? a1 : a2;
        bool cand = act && (wm == eC);      // no strictly-larger in window
        u64 Mc = __ballot((int)cand);
        u64 M = 0;
        while (Mc) {                        // exact tie-break (rare >1 iter)
            int c = __ffsll((long long)Mc) - 1;
            Mc &= Mc - 1;
            u32 vc = readlane32(eC, c);
            u64 eqC = __ballot((int)(eC == vc));   // own chunk, natural order
            u64 eqP = __ballot((int)(ePr == vc));  // prev, bit l<->prev[63-l]
            int lo = c - 32; if (lo < 0) lo = 0;
            u64 belowC = (c == 0) ? 0ULL
                       : (((1ULL << c) - 1ULL) & ~((1ULL << lo) - 1ULL));
            u64 blockP = (c <= 31) ? (eqP & ((1ULL << (32 - c)) - 1ULL)) : 0ULL;
            if (((eqC & belowC) | blockP) == 0ULL) M |= (1ULL << c);
        }
        if (M == 0ULL) { conv = true; break; }
        bool winlane = (M >> lane) & 1ULL;
        if (winlane) { eC = SENT32; alive &= ~SELF; act = false; }   // write deferred
        // ballot-mask suppression; own-chunk writes deferred, neighbor immediate
        int lo = lane - 32; if (lo < 0) lo = 0;
        int hi = lane + 32; if (hi > 63) hi = 63;
        u64 mwin = ((hi == 63) ? ~0ULL : ((1ULL << (hi + 1)) - 1ULL))
                 & ~((1ULL << lo) - 1ULL);
        bool supS = !winlane && ((M & mwin & ~(1ULL << lane)) != 0ULL);
        bool supP = (lane >= 32) && ((M & ((1ULL << (lane - 31)) - 1ULL)) != 0ULL);
        bool supN = (lane < 32) && ((M & (~0ULL << (lane + 32))) != 0ULL);
        if (supS) { eC = 0u; alive &= ~SELF; act = false; }
        if (supP) {
            enc[p - 64] = 0u; eP = 0u;
            if constexpr (KL > 0) alive &= ~(1u << KLm1);
        }
        if (supN) {
            enc[p + 64] = 0u; eN = 0u;
            if constexpr (KL < CPW - 1) alive &= ~(1u << KLp1);
        }
        u64 bP = __ballot((int)supP);
        u64 bN = __ballot((int)supN);
        anyP |= (bP != 0ULL);
        anyN |= (bN != 0ULL);
        if (!__ballot((int)act)) { conv = true; break; }
        if (bP) { ePr = rev64(eP, lane); S_P = scanmax32(ePr); }
        if (bN) { P_n = scanmax32(eN); }
    }
    // batched own-chunk flush (per-lane predicated)
    u64 chg = __ballot((int)(eC != eC0));
    if (eC != eC0) enc[p] = eC;
    // exact dirty propagation
    if ((((u32)chg != 0u) && (DLO != 0u)) || (anyP && (KL > 0))) dirty |= DLO;
    if ((((u32)(chg >> 32) != 0u) && (DHI != 0u)) || (anyN && (KL < CPW - 1))) dirty |= DHI;
    if (conv) dirty &= ~SELF; else dirty |= SELF;   // rep-exhaust: stay dirty
    // write back register-carried state
    own = eC;
    if constexpr (KL > 0) prevR = eP;
    if constexpr (KL < CPW - 1) nextR = eN;
    if constexpr (KL == 0) ePb = eP;   // own supP writes are not external changes
    if constexpr (KL == CPW - 1) eNb = eN;
}

template<int KL>
static __device__ __forceinline__ void sweep_fwd(u32* enc, int seg0, int lane,
        u32& alive, u32& dirty, u32 (&r)[CPW], u32& ePb, u32& eNb) {
    visit<KL>(enc, seg0, lane, alive, dirty, r, ePb, eNb);
    if constexpr (KL < CPW - 1)
        sweep_fwd<KL + 1>(enc, seg0, lane, alive, dirty, r, ePb, eNb);
}
template<int KL>
static __device__ __forceinline__ void sweep_bwd(u32* enc, int seg0, int lane,
        u32& alive, u32& dirty, u32 (&r)[CPW], u32& ePb, u32& eNb) {
    visit<KL>(enc, seg0, lane, alive, dirty, r, ePb, eNb);
    if constexpr (KL > 0)
        sweep_bwd<KL - 1>(enc, seg0, lane, alive, dirty, r, ePb, eNb);
}

__global__ __launch_bounds__(BLOCK)
void extrema1d_kernel(const float* __restrict__ x,
                      const int* __restrict__ dptr,
                      float* __restrict__ out) {
    __shared__ float s_x[L];
    __shared__ u32 s_enc_raw[L + 2 * DPAD];
    __shared__ u64 s_enc64_raw[L + 2 * DPAD];  // generic-d fallback only
    u32* enc = s_enc_raw + DPAD;

    const int row = blockIdx.x;
    const int tid = threadIdx.x;
    const int lane = tid & (LANES - 1);
    const int wave = tid >> 6;
    const int d = *dptr;
    const float* __restrict__ xrow = x + (size_t)row * L;

    // ---- stage row (coalesced float4) ----
    #pragma unroll
    for (int k = 0; k < VPT; ++k)
        ((float4*)s_x)[tid + k * BLOCK] = ((const float4*)xrow)[tid + k * BLOCK];
    if (tid < 2 * DPAD)
        s_enc_raw[(tid < DPAD) ? tid : (DPAD + L + (tid - DPAD))] = 0u;
    __syncthreads();

    // ---- extrema -> keys (reference pads: dxr[L-1]=F, dxl[0]=T, neg=!(x>0))
    #pragma unroll
    for (int k = 0; k < VPT; ++k) {
        int vi = tid + k * BLOCK;
        int base = 4 * vi;
        float4 xv = ((const float4*)s_x)[vi];
        float xl = (base == 0) ? 0.0f : s_x[base - 1];
        float xr = (base + 4 >= L) ? 0.0f : s_x[base + 4];
        float nb[6] = {xl, xv.x, xv.y, xv.z, xv.w, xr};
        uint4 ev; u32* evp = (u32*)&ev;
        #pragma unroll
        for (int j = 0; j < 4; ++j) {
            int p = base + j;
            float xi = nb[j + 1];
            bool dxr = (p < L - 1) && ((nb[j + 2] - xi) > 0.0f);
            bool dxl = (p == 0) || ((xi - nb[j]) <= 0.0f);
            bool neg = !(xi > 0.0f);
            bool ext = (dxr && dxl && neg) || (!dxr && !dxl && !neg);
            evp[j] = ext ? (__float_as_uint(fabsf(xi)) + 1u) : 0u;
        }
        ((uint4*)&enc[base])[0] = ev;
    }
    __syncthreads();

    if (d == 32) {
        const int seg0 = wave * CPW;
        u32 alive = (1u << CPW) - 1u;   // bit kl <-> pos (seg0+kl)*64+lane
        u32 dirty = alive;
        u32 ePb = 0u, eNb = 0u;         // cached external boundary views
        u32 r[CPW];                      // register-carried chunk states
        #pragma unroll
        for (int i = 0; i < CPW; ++i) r[i] = enc[((seg0 + i) << 6) + lane];
        int dir = 0;
        for (int pass = 0; pass < 512; ++pass) {
            if (!__ballot((int)(alive != 0u))) break;
            if ((pass & 31) == 31) dirty = (1u << CPW) - 1u;  // livelock insurance
            if (dir == 0) sweep_fwd<0>(enc, seg0, lane, alive, dirty, r, ePb, eNb);
            else          sweep_bwd<CPW - 1>(enc, seg0, lane, alive, dirty, r, ePb, eNb);
            __threadfence_block();
            dir ^= 1;
        }
    } else if (wave == 0) {
        // ---- generic-d exact fallback: single wave, u64 keys ----
        u64* enc64 = s_enc64_raw + DPAD;
        for (int k = 0; k < NCH; ++k) {
            int p = (k << 6) + lane;
            u32 e = enc[p];
            enc64[p] = e ? ((((u64)e) << 12) | (u64)(4095 - p)) : 0ULL;
        }
        s_enc64_raw[lane] = 0;
        s_enc64_raw[L + DPAD + lane] = 0;
        u64 alive64 = ~0ULL;
        int dir = 0;
        for (int pass = 0; pass < 2048; ++pass) {
            if (!__ballot((int)(alive64 != 0ULL))) break;
            for (int kk = 0; kk < NCH; ++kk) {
                int k = dir ? (NCH - 1 - kk) : kk;
                bool act = (alive64 >> k) & 1ULL;
                if (!__ballot((int)act)) continue;
                int p = (k << 6) + lane;
                u64 me = 0;
                if (act) {
                    me = enc64[p];
                    if (me == 0ULL) { alive64 &= ~(1ULL << k); act = false; }
                }
                if (!__ballot((int)act)) continue;
                u64 best = 0;
                int lo = p - d; if (lo < 0) lo = 0;
                int hi = p + d; if (hi > L - 1) hi = L - 1;
                if (act)
                    for (int j = lo; j <= hi; ++j)
                        if (j != p) best = best > enc64[j] ? best : enc64[j];
                if (act && best < me) {
                    enc64[p] = ~0ULL;
                    enc[p] = SENT32;
                    alive64 &= ~(1ULL << k);
                    for (int j = lo; j <= hi; ++j)
                        if (j != p) enc64[j] = 0ULL;
                }
            }
            dir ^= 1;
        }
    }
    __syncthreads();

    // ---- emit: kept -> x, else 0 ----
    float* __restrict__ orow = out + (size_t)row * L;
    #pragma unroll
    for (int k = 0; k < VPT; ++k) {
        int vi = tid + k * BLOCK;
        uint4 ev = ((const uint4*)&enc[4 * vi])[0];
        float4 xv = ((const float4*)s_x)[vi];
        float4 o;
        o.x = (ev.x == SENT32) ? xv.x : 0.0f;
        o.y = (ev.y == SENT32) ? xv.y : 0.0f;
        o.z = (ev.z == SENT32) ? xv.z : 0.0f;
        o.w = (ev.w == SENT32) ? xv.w : 0.0f;
        ((float4*)orow)[vi] = o;
    }
}

extern "C" void kernel_launch(void* const* d_in, const int* in_sizes, int n_in,
                              void* d_out, int out_size, void* d_ws, size_t ws_size,
                              hipStream_t stream) {
    const float* x = (const float*)d_in[0];
    const int* dptr = (const int*)d_in[1];
    float* out = (float*)d_out;
    const int B = out_size / L;  // 128 rows, 4 waves each
    extrema1d_kernel<<<B, BLOCK, 0, stream>>>(x, dptr, out);
}

// Round 6
// 62.027 us; speedup vs baseline: 1.2763x; 1.2763x over previous
//
#include <hip/hip_runtime.h>

#define L 4096
#define BLOCK 1024
#define LANES 64
#define NWAVE (BLOCK / LANES)     // 16 waves per row
#define NCH (L / LANES)           // 64 chunks of 64
#define CPW (NCH / NWAVE)         // 4 chunks per wave (contiguous segment)
#define DPAD 64
typedef unsigned long long u64;
typedef unsigned u32;
#define SENT32 0xFFFFFFFFu        // kept marker; real keys <= 0x7F800002

template<int CTRL, int RM>
static __device__ __forceinline__ u32 dpp32(u32 v) {
    u32 s = (u32)__builtin_amdgcn_update_dpp(0, (int)v, CTRL, RM, 0xf, false);
    return v > s ? v : s;   // bound_ctrl=false, old=0 -> identity off-row
}
// Inclusive 64-lane prefix-max (R4..R8-verified DPP sequence).
static __device__ __forceinline__ u32 scanmax32(u32 v) {
    v = dpp32<0x111, 0xf>(v);  // row_shr:1
    v = dpp32<0x112, 0xf>(v);  // row_shr:2
    v = dpp32<0x114, 0xf>(v);  // row_shr:4
    v = dpp32<0x118, 0xf>(v);  // row_shr:8
    v = dpp32<0x142, 0xa>(v);  // row_bcast:15
    v = dpp32<0x143, 0xc>(v);  // row_bcast:31
    return v;
}
static __device__ __forceinline__ u32 rev64(u32 v, int lane) {
    return (u32)__shfl((int)v, 63 - lane);
}

// enc[i]: active -> bits(|x|)+1; 0 = none/suppressed; SENT32 = kept.
// Register-carry soundness: cross-wave writes reach only chunk0's lower 32 /
// chunk3's upper 32 slots (winners live in their own segment, radius 32).
// Those slots are outside every window of inner-chunk items, so inner chunks'
// decision inputs carried in registers are EXACT; boundary chunks (0,3) are
// re-read fresh from LDS each visit. Out-of-window staleness only
// over-estimates dead neighbors -> defer-only, never a false keep; ties
// resolved exactly via equality ballots (smaller index first = JAX argsort).
template<int KL>
static __device__ __forceinline__ void visit(u32* enc, int seg0, int lane,
                                             u32& alive,
                                             u32& r0, u32& r1, u32& r2, u32& r3) {
    if (!__ballot((int)((alive >> KL) & 1u))) return;
    const int q0 = (seg0 + KL) << 6;
    const int p = q0 + lane;
    u32& own   = (KL == 0) ? r0 : (KL == 1) ? r1 : (KL == 2) ? r2 : r3;
    u32 dumP = 0, dumN = 0;
    u32& prevR = (KL == 0) ? dumP : (KL == 1) ? r0 : (KL == 2) ? r1 : r2;
    u32& nextR = (KL == 3) ? dumN : (KL == 0) ? r1 : (KL == 1) ? r2 : r3;

    u32 eC;
    if constexpr (KL == 0 || KL == 3) eC = ((volatile u32*)enc)[p];
    else eC = own;
    bool act = (alive >> KL) & 1u;
    if (act && eC == 0u) { alive &= ~(1u << KL); act = false; }
    if (!__ballot((int)act)) { own = eC; return; }

    u32 eP, eN;
    if constexpr (KL == 0) eP = ((volatile u32*)enc)[q0 - 64 + lane];
    else eP = prevR;
    if constexpr (KL == 3) eN = ((volatile u32*)enc)[q0 + 64 + lane];
    else eN = nextR;

    u32 ePr = rev64(eP, lane);
    u32 S_P = scanmax32(ePr);
    u32 P_n = scanmax32(eN);

    for (int rep = 0; rep < 3; ++rep) {
        u32 P_c = scanmax32(eC);
        u32 S_C = scanmax32(rev64(eC, lane));
        // Gil-Werman window-max [p-32,p+32]
        u32 sendS = (lane < 32) ? S_P : S_C;
        u32 sendP = (lane < 32) ? P_n : P_c;
        int idxP = lane ^ 32;
        u32 a1 = (u32)__shfl((int)sendS, 63 - idxP);
        u32 a2 = (u32)__shfl((int)sendP, idxP);
        u32 wm = a1 > a2 ? a1 : a2;
        bool cand = act && (wm == eC);      // no strictly-larger in window
        u64 Mc = __ballot((int)cand);
        u64 M = 0;
        while (Mc) {                        // exact tie-break (rare >1 iter)
            int c = __ffsll((long long)Mc) - 1;
            Mc &= Mc - 1;
            u32 vc = (u32)__shfl((int)eC, c);
            u64 eqC = __ballot((int)(eC == vc));   // own chunk, natural order
            u64 eqP = __ballot((int)(ePr == vc));  // prev, bit l<->prev[63-l]
            int lo = c - 32; if (lo < 0) lo = 0;
            u64 belowC = (c == 0) ? 0ULL
                       : (((1ULL << c) - 1ULL) & ~((1ULL << lo) - 1ULL));
            u64 blockP = (c <= 31) ? (eqP & ((1ULL << (32 - c)) - 1ULL)) : 0ULL;
            if (((eqC & belowC) | blockP) == 0ULL) M |= (1ULL << c);
        }
        if (M == 0ULL) break;
        bool winlane = (M >> lane) & 1ULL;
        if (winlane) { enc[p] = SENT32; eC = SENT32; alive &= ~(1u << KL); act = false; }
        // ballot-mask suppression: up to 3 predicated LDS writes per lane
        int lo = lane - 32; if (lo < 0) lo = 0;
        int hi = lane + 32; if (hi > 63) hi = 63;
        u64 mwin = ((hi == 63) ? ~0ULL : ((1ULL << (hi + 1)) - 1ULL))
                 & ~((1ULL << lo) - 1ULL);
        bool supS = !winlane && ((M & mwin & ~(1ULL << lane)) != 0ULL);
        bool supP = (lane >= 32) && ((M & ((1ULL << (lane - 31)) - 1ULL)) != 0ULL);
        bool supN = (lane < 32) && ((M & (~0ULL << (lane + 32))) != 0ULL);
        if (supS) { enc[p] = 0u; eC = 0u; alive &= ~(1u << KL); act = false; }
        if (supP) { enc[p - 64] = 0u; eP = 0u; if (KL > 0) alive &= ~(1u << (KL - 1)); }
        if (supN) { enc[p + 64] = 0u; eN = 0u; if (KL < 3) alive &= ~(1u << (KL + 1)); }
        if (!__ballot((int)act)) break;
        if (__ballot((int)supP)) { ePr = rev64(eP, lane); S_P = scanmax32(ePr); }
        if (__ballot((int)supN)) { P_n = scanmax32(eN); }
    }
    // write back register-carried state
    own = eC;
    if constexpr (KL > 0) prevR = eP;
    if constexpr (KL < 3) nextR = eN;
}

__global__ __launch_bounds__(BLOCK)
void extrema1d_kernel(const float* __restrict__ x,
                      const int* __restrict__ dptr,
                      float* __restrict__ out) {
    __shared__ float s_x[L];
    __shared__ u32 s_enc_raw[L + 2 * DPAD];
    __shared__ u64 s_enc64_raw[L + 2 * DPAD];  // generic-d fallback only
    u32* enc = s_enc_raw + DPAD;

    const int row = blockIdx.x;
    const int tid = threadIdx.x;
    const int lane = tid & (LANES - 1);
    const int wave = tid >> 6;
    const int d = *dptr;
    const float* __restrict__ xrow = x + (size_t)row * L;

    // ---- stage row (coalesced float4, 1 per thread) ----
    ((float4*)s_x)[tid] = ((const float4*)xrow)[tid];
    if (tid < 2 * DPAD)
        s_enc_raw[(tid < DPAD) ? tid : (DPAD + L + (tid - DPAD))] = 0u;
    __syncthreads();

    // ---- extrema -> keys (reference pads: dxr[L-1]=F, dxl[0]=T, neg=!(x>0))
    {
        int base = 4 * tid;
        float4 xv = ((const float4*)s_x)[tid];
        float xl = (base == 0) ? 0.0f : s_x[base - 1];
        float xr = (base + 4 >= L) ? 0.0f : s_x[base + 4];
        float nb[6] = {xl, xv.x, xv.y, xv.z, xv.w, xr};
        uint4 ev; u32* evp = (u32*)&ev;
        #pragma unroll
        for (int j = 0; j < 4; ++j) {
            int p = base + j;
            float xi = nb[j + 1];
            bool dxr = (p < L - 1) && ((nb[j + 2] - xi) > 0.0f);
            bool dxl = (p == 0) || ((xi - nb[j]) <= 0.0f);
            bool neg = !(xi > 0.0f);
            bool ext = (dxr && dxl && neg) || (!dxr && !dxl && !neg);
            evp[j] = ext ? (__float_as_uint(fabsf(xi)) + 1u) : 0u;
        }
        ((uint4*)&enc[base])[0] = ev;
    }
    __syncthreads();

    if (d == 32) {
        const int seg0 = wave * CPW;
        u32 alive = (1u << CPW) - 1u;   // bit kl <-> pos (seg0+kl)*64+lane
        // register-carried chunk states
        u32 r0 = enc[((seg0 + 0) << 6) + lane];
        u32 r1 = enc[((seg0 + 1) << 6) + lane];
        u32 r2 = enc[((seg0 + 2) << 6) + lane];
        u32 r3 = enc[((seg0 + 3) << 6) + lane];
        int dir = 0;
        for (int pass = 0; pass < 512; ++pass) {
            if (!__ballot((int)(alive != 0u))) break;
            if (dir == 0) {
                visit<0>(enc, seg0, lane, alive, r0, r1, r2, r3);
                visit<1>(enc, seg0, lane, alive, r0, r1, r2, r3);
                visit<2>(enc, seg0, lane, alive, r0, r1, r2, r3);
                visit<3>(enc, seg0, lane, alive, r0, r1, r2, r3);
            } else {
                visit<3>(enc, seg0, lane, alive, r0, r1, r2, r3);
                visit<2>(enc, seg0, lane, alive, r0, r1, r2, r3);
                visit<1>(enc, seg0, lane, alive, r0, r1, r2, r3);
                visit<0>(enc, seg0, lane, alive, r0, r1, r2, r3);
            }
            __threadfence_block();
            dir ^= 1;
        }
    } else if (wave == 0) {
        // ---- generic-d exact fallback: single wave, u64 keys ----
        u64* enc64 = s_enc64_raw + DPAD;
        for (int k = 0; k < NCH; ++k) {
            int p = (k << 6) + lane;
            u32 e = enc[p];
            enc64[p] = e ? ((((u64)e) << 12) | (u64)(4095 - p)) : 0ULL;
        }
        s_enc64_raw[lane] = 0;
        s_enc64_raw[L + DPAD + lane] = 0;
        u64 alive64 = ~0ULL;
        int dir = 0;
        for (int pass = 0; pass < 2048; ++pass) {
            if (!__ballot((int)(alive64 != 0ULL))) break;
            for (int kk = 0; kk < NCH; ++kk) {
                int k = dir ? (NCH - 1 - kk) : kk;
                bool act = (alive64 >> k) & 1ULL;
                if (!__ballot((int)act)) continue;
                int p = (k << 6) + lane;
                u64 me = 0;
                if (act) {
                    me = enc64[p];
                    if (me == 0ULL) { alive64 &= ~(1ULL << k); act = false; }
                }
                if (!__ballot((int)act)) continue;
                u64 best = 0;
                int lo = p - d; if (lo < 0) lo = 0;
                int hi = p + d; if (hi > L - 1) hi = L - 1;
                if (act)
                    for (int j = lo; j <= hi; ++j)
                        if (j != p) best = best > enc64[j] ? best : enc64[j];
                if (act && best < me) {
                    enc64[p] = ~0ULL;
                    enc[p] = SENT32;
                    alive64 &= ~(1ULL << k);
                    for (int j = lo; j <= hi; ++j)
                        if (j != p) enc64[j] = 0ULL;
                }
            }
            dir ^= 1;
        }
    }
    __syncthreads();

    // ---- emit: kept -> x, else 0 ----
    float* __restrict__ orow = out + (size_t)row * L;
    {
        uint4 ev = ((const uint4*)&enc[4 * tid])[0];
        float4 xv = ((const float4*)s_x)[tid];
        float4 o;
        o.x = (ev.x == SENT32) ? xv.x : 0.0f;
        o.y = (ev.y == SENT32) ? xv.y : 0.0f;
        o.z = (ev.z == SENT32) ? xv.z : 0.0f;
        o.w = (ev.w == SENT32) ? xv.w : 0.0f;
        ((float4*)orow)[tid] = o;
    }
}

extern "C" void kernel_launch(void* const* d_in, const int* in_sizes, int n_in,
                              void* d_out, int out_size, void* d_ws, size_t ws_size,
                              hipStream_t stream) {
    const float* x = (const float*)d_in[0];
    const int* dptr = (const int*)d_in[1];
    float* out = (float*)d_out;
    const int B = out_size / L;  // 128 rows, 16 waves each
    extrema1d_kernel<<<B, BLOCK, 0, stream>>>(x, dptr, out);
}